// Round 9
// baseline (23.633 us; speedup 1.0000x reference)
//
#include <hip/hip_runtime.h>

constexpr int BATCH = 4;
constexpr int NBOX  = 2048;
constexpr int TPB   = 512;             // 8 waves; block owns full rows
constexpr int JQ    = 4;               // j's per thread -> 16B stores
constexpr int ITILE = 16;              // full rows per block
constexpr float NL8E = -0.18033688011112042f;  // -log2(e)/8

typedef float f32x4 __attribute__((ext_vector_type(4)));

// ---- per-box params: u, A=s00/2, B=s01/2, D=s11/2, R=(det sigma)^{1/4} ----
__device__ __forceinline__ void box_params(
        const float4* __restrict__ bb4, const float* __restrict__ angles, int idx,
        float& cx, float& cy, float& A, float& B, float& D, float& R) {
    float4 p01 = bb4[2 * idx];
    float4 p23 = bb4[2 * idx + 1];

    cx = (p01.x + p01.z + p23.x + p23.z) * 0.25f;
    cy = (p01.y + p01.w + p23.y + p23.w) * 0.25f;

    float ang = angles[idx];
    float s = __sinf(ang);
    float c = __cosf(ang);

    float dx0 = p01.x - cx, dy0 = p01.y - cy;
    float dx1 = p01.z - cx, dy1 = p01.w - cy;
    float dx2 = p23.x - cx, dy2 = p23.y - cy;
    float dx3 = p23.z - cx, dy3 = p23.w - cy;

    float px0 = dx0 * c - dy0 * s, py0 = dx0 * s + dy0 * c;
    float px1 = dx1 * c - dy1 * s, py1 = dx1 * s + dy1 * c;
    float px2 = dx2 * c - dy2 * s, py2 = dx2 * s + dy2 * c;
    float px3 = dx3 * c - dy3 * s, py3 = dx3 * s + dy3 * c;

    float minx = fminf(fminf(px0, px1), fminf(px2, px3));
    float maxx = fmaxf(fmaxf(px0, px1), fmaxf(px2, px3));
    float miny = fminf(fminf(py0, py1), fminf(py2, py3));
    float maxy = fmaxf(fmaxf(py0, py1), fmaxf(py2, py3));

    float w0 = (maxx - minx) * 0.5f;
    float w1 = (maxy - miny) * 0.5f;

    A = 0.5f * (c * c * w0 + s * s * w1);
    B = 0.5f * (c * s * (w0 - w1));
    D = 0.5f * (s * s * w0 + c * c * w1);
    R = __builtin_amdgcn_sqrtf(__builtin_amdgcn_sqrtf(w0 * w1));  // det^(1/4)
}

__device__ __forceinline__ float2 f2(float x, float y) { return make_float2(x, y); }
__device__ __forceinline__ float2 add2(float2 a, float2 b) { return f2(a.x + b.x, a.y + b.y); }
__device__ __forceinline__ float2 sub2(float2 a, float2 b) { return f2(a.x - b.x, a.y - b.y); }
__device__ __forceinline__ float2 mul2(float2 a, float2 b) { return f2(a.x * b.x, a.y * b.y); }
__device__ __forceinline__ float2 fma2(float2 a, float2 b, float2 c) {
    return f2(__builtin_fmaf(a.x, b.x, c.x), __builtin_fmaf(a.y, b.y, c.y));
}

// two pairs at once: wave-uniform i-params vs a float2 of j-params
__device__ __forceinline__ float2 pair_duo(
        float iux, float iuy, float ia, float ib, float id, float ir,
        float2 jux, float2 juy, float2 ja, float2 jb, float2 jd, float2 jr) {
    float2 ddx = sub2(f2(iux, iux), jux);
    float2 ddy = sub2(f2(iuy, iuy), juy);
    float2 a   = add2(f2(ia, ia), ja);
    float2 bb  = add2(f2(ib, ib), jb);
    float2 d   = add2(f2(id, id), jd);

    float2 mb2 = mul2(bb, bb);
    float2 det = fma2(a, d, f2(-mb2.x, -mb2.y));
    float2 rsq = f2(__builtin_amdgcn_rsqf(det.x), __builtin_amdgcn_rsqf(det.y));
    float2 inv = mul2(rsq, rsq);

    float2 q   = fma2(mul2(ddy, ddy), a, mul2(mul2(ddx, ddx), d));
    float2 e   = mul2(mul2(q, inv), f2(NL8E, NL8E));
    float2 ex  = f2(__builtin_amdgcn_exp2f(e.x), __builtin_amdgcn_exp2f(e.y));

    float2 bc  = mul2(mul2(ex, rsq), mul2(f2(ir, ir), jr));
    float2 om  = f2(fmaxf(1.0f - bc.x, 1e-12f), fmaxf(1.0f - bc.y, 1e-12f));
    float2 hd  = f2(__builtin_amdgcn_sqrtf(om.x), __builtin_amdgcn_sqrtf(om.y));
    return f2(1.0f - hd.x, 1.0f - hd.y);
}

__global__ __launch_bounds__(TPB, 8) void fused_iou(
        const float* __restrict__ bboxes,
        const float* __restrict__ angles,
        float* __restrict__ out) {
    const int tid = threadIdx.x;
    const int b   = blockIdx.y;
    const int i0  = blockIdx.x * ITILE;
    const int j0  = tid * JQ;                 // block spans the full row

    const float4* bb4 = reinterpret_cast<const float4*>(bboxes);

    // i-params packed [ITILE][8]: (ux,uy,A,B) | (D,R,pad,pad)
    __shared__ float sp[ITILE][8];
    if (tid < ITILE) {
        float cx, cy, A, B, D, R;
        box_params(bb4, angles, b * NBOX + i0 + tid, cx, cy, A, B, D, R);
        sp[tid][0] = cx; sp[tid][1] = cy; sp[tid][2] = A; sp[tid][3] = B;
        sp[tid][4] = D;  sp[tid][5] = R;  sp[tid][6] = 0.f; sp[tid][7] = 0.f;
    }

    // j-params: each thread computes its own 4 boxes into registers
    float2 jux[2], juy[2], jA[2], jB[2], jD[2], jR[2];
    #pragma unroll
    for (int h = 0; h < 2; ++h) {
        float c0, c1, y0v, y1v, A0, A1, B0, B1, D0, D1, R0, R1;
        box_params(bb4, angles, b * NBOX + j0 + 2 * h + 0, c0, y0v, A0, B0, D0, R0);
        box_params(bb4, angles, b * NBOX + j0 + 2 * h + 1, c1, y1v, A1, B1, D1, R1);
        jux[h] = f2(c0, c1); juy[h] = f2(y0v, y1v);
        jA[h] = f2(A0, A1);  jB[h] = f2(B0, B1);
        jD[h] = f2(D0, D1);  jR[h] = f2(R0, R1);
    }

    __syncthreads();

    float* orow = out + ((size_t)(b * NBOX + i0)) * NBOX + j0;

    #pragma unroll 4
    for (int it = 0; it < ITILE; ++it) {
        float4 p0 = *reinterpret_cast<const float4*>(&sp[it][0]);
        float2 p1 = *reinterpret_cast<const float2*>(&sp[it][4]);

        float2 rlo = pair_duo(p0.x, p0.y, p0.z, p0.w, p1.x, p1.y,
                              jux[0], juy[0], jA[0], jB[0], jD[0], jR[0]);
        float2 rhi = pair_duo(p0.x, p0.y, p0.z, p0.w, p1.x, p1.y,
                              jux[1], juy[1], jA[1], jB[1], jD[1], jR[1]);

        // 16B/lane NORMAL store (L2 write-combining); block writes full 8KB row
        f32x4 rv;
        rv.x = rlo.x; rv.y = rlo.y; rv.z = rhi.x; rv.w = rhi.y;
        *reinterpret_cast<f32x4*>(orow) = rv;
        orow += NBOX;
    }
}

extern "C" void kernel_launch(void* const* d_in, const int* in_sizes, int n_in,
                              void* d_out, int out_size, void* d_ws, size_t ws_size,
                              hipStream_t stream) {
    const float* bboxes = (const float*)d_in[0];
    const float* angles = (const float*)d_in[1];
    float* out = (float*)d_out;

    dim3 g(NBOX / ITILE, BATCH);   // 128 x 4 = 512 blocks, 16 full rows each
    fused_iou<<<g, TPB, 0, stream>>>(bboxes, angles, out);
}

// Round 10
// 21.624 us; speedup vs baseline: 1.0929x; 1.0929x over previous
//
#include <hip/hip_runtime.h>

constexpr int BATCH = 4;
constexpr int NBOX  = 2048;
constexpr int TPB   = 256;
constexpr int JQ    = 2;                // j's per thread (keeps VGPR <= 64)
constexpr int JSPAN = TPB * JQ;         // 512 j per block
constexpr int ITILE = 16;               // i rows per block
constexpr float NL8E = -0.18033688011112042f;  // -log2(e)/8

typedef float f32x2 __attribute__((ext_vector_type(2)));

// ---- per-box params: u, A=s00/2, B=s01/2, D=s11/2, R=(det sigma)^{1/4} ----
__device__ __forceinline__ void box_params(
        const float4* __restrict__ bb4, const float* __restrict__ angles, int idx,
        float& cx, float& cy, float& A, float& B, float& D, float& R) {
    float4 p01 = bb4[2 * idx];
    float4 p23 = bb4[2 * idx + 1];

    cx = (p01.x + p01.z + p23.x + p23.z) * 0.25f;
    cy = (p01.y + p01.w + p23.y + p23.w) * 0.25f;

    float ang = angles[idx];
    float s = __sinf(ang);
    float c = __cosf(ang);

    float dx0 = p01.x - cx, dy0 = p01.y - cy;
    float dx1 = p01.z - cx, dy1 = p01.w - cy;
    float dx2 = p23.x - cx, dy2 = p23.y - cy;
    float dx3 = p23.z - cx, dy3 = p23.w - cy;

    float px0 = dx0 * c - dy0 * s, py0 = dx0 * s + dy0 * c;
    float px1 = dx1 * c - dy1 * s, py1 = dx1 * s + dy1 * c;
    float px2 = dx2 * c - dy2 * s, py2 = dx2 * s + dy2 * c;
    float px3 = dx3 * c - dy3 * s, py3 = dx3 * s + dy3 * c;

    float minx = fminf(fminf(px0, px1), fminf(px2, px3));
    float maxx = fmaxf(fmaxf(px0, px1), fmaxf(px2, px3));
    float miny = fminf(fminf(py0, py1), fminf(py2, py3));
    float maxy = fmaxf(fmaxf(py0, py1), fmaxf(py2, py3));

    float w0 = (maxx - minx) * 0.5f;
    float w1 = (maxy - miny) * 0.5f;

    A = 0.5f * (c * c * w0 + s * s * w1);
    B = 0.5f * (c * s * (w0 - w1));
    D = 0.5f * (s * s * w0 + c * c * w1);
    R = __builtin_amdgcn_sqrtf(__builtin_amdgcn_sqrtf(w0 * w1));  // det^(1/4)
}

// ---- float2 helpers (encourage v_pk_*_f32 packed math) ----
__device__ __forceinline__ float2 f2(float x, float y) { return make_float2(x, y); }
__device__ __forceinline__ float2 add2(float2 a, float2 b) { return f2(a.x + b.x, a.y + b.y); }
__device__ __forceinline__ float2 sub2(float2 a, float2 b) { return f2(a.x - b.x, a.y - b.y); }
__device__ __forceinline__ float2 mul2(float2 a, float2 b) { return f2(a.x * b.x, a.y * b.y); }
__device__ __forceinline__ float2 fma2(float2 a, float2 b, float2 c) {
    return f2(__builtin_fmaf(a.x, b.x, c.x), __builtin_fmaf(a.y, b.y, c.y));
}

// two pairs at once: wave-uniform i-params vs a float2 of j-params
__device__ __forceinline__ float2 pair_duo(
        float iux, float iuy, float ia, float ib, float id, float ir,
        float2 jux, float2 juy, float2 ja, float2 jb, float2 jd, float2 jr) {
    float2 ddx = sub2(f2(iux, iux), jux);
    float2 ddy = sub2(f2(iuy, iuy), juy);
    float2 a   = add2(f2(ia, ia), ja);
    float2 bb  = add2(f2(ib, ib), jb);
    float2 d   = add2(f2(id, id), jd);

    float2 mb2 = mul2(bb, bb);
    float2 det = fma2(a, d, f2(-mb2.x, -mb2.y));
    float2 rsq = f2(__builtin_amdgcn_rsqf(det.x), __builtin_amdgcn_rsqf(det.y));
    float2 inv = mul2(rsq, rsq);

    float2 q   = fma2(mul2(ddy, ddy), a, mul2(mul2(ddx, ddx), d));
    float2 e   = mul2(mul2(q, inv), f2(NL8E, NL8E));
    float2 ex  = f2(__builtin_amdgcn_exp2f(e.x), __builtin_amdgcn_exp2f(e.y));

    float2 bc  = mul2(mul2(ex, rsq), mul2(f2(ir, ir), jr));
    float2 om  = f2(fmaxf(1.0f - bc.x, 1e-12f), fmaxf(1.0f - bc.y, 1e-12f));
    float2 hd  = f2(__builtin_amdgcn_sqrtf(om.x), __builtin_amdgcn_sqrtf(om.y));
    return f2(1.0f - hd.x, 1.0f - hd.y);
}

__global__ __launch_bounds__(TPB, 8) void fused_iou(
        const float* __restrict__ bboxes,
        const float* __restrict__ angles,
        float* __restrict__ out) {
    const int tid = threadIdx.x;
    const int b   = blockIdx.z;
    const int i0  = blockIdx.y * ITILE;
    const int j0  = blockIdx.x * JSPAN + tid * JQ;

    const float4* bb4 = reinterpret_cast<const float4*>(bboxes);

    // i-params: 16 lanes of wave 0 -> LDS (other waves proceed to j-params)
    __shared__ float sp[6][ITILE];
    if (tid < ITILE) {
        float cx, cy, A, B, D, R;
        box_params(bb4, angles, b * NBOX + i0 + tid, cx, cy, A, B, D, R);
        sp[0][tid] = cx; sp[1][tid] = cy; sp[2][tid] = A;
        sp[3][tid] = B;  sp[4][tid] = D;  sp[5][tid] = R;
    }

    // j-params: each thread computes its own 2 boxes into registers
    float c0, c1, y0v, y1v, A0, A1, B0, B1, D0, D1, R0, R1;
    box_params(bb4, angles, b * NBOX + j0 + 0, c0, y0v, A0, B0, D0, R0);
    box_params(bb4, angles, b * NBOX + j0 + 1, c1, y1v, A1, B1, D1, R1);
    float2 jux = f2(c0, c1);
    float2 juy = f2(y0v, y1v);
    float2 jA  = f2(A0, A1);
    float2 jB  = f2(B0, B1);
    float2 jD  = f2(D0, D1);
    float2 jR  = f2(R0, R1);

    __syncthreads();

    float* orow = out + ((size_t)(b * NBOX + i0)) * NBOX + j0;

    #pragma unroll 4
    for (int it = 0; it < ITILE; ++it) {
        float iux = sp[0][it];   // all-lane broadcast, conflict-free
        float iuy = sp[1][it];
        float ia  = sp[2][it];
        float ibv = sp[3][it];
        float id  = sp[4][it];
        float ir  = sp[5][it];

        float2 r = pair_duo(iux, iuy, ia, ibv, id, ir, jux, juy, jA, jB, jD, jR);

        // streaming output, never re-read: bypass L2/L3 allocation
        f32x2 rv;
        rv.x = r.x; rv.y = r.y;
        __builtin_nontemporal_store(rv, reinterpret_cast<f32x2*>(orow));
        orow += NBOX;
    }
}

extern "C" void kernel_launch(void* const* d_in, const int* in_sizes, int n_in,
                              void* d_out, int out_size, void* d_ws, size_t ws_size,
                              hipStream_t stream) {
    const float* bboxes = (const float*)d_in[0];
    const float* angles = (const float*)d_in[1];
    float* out = (float*)d_out;

    dim3 g(NBOX / JSPAN, NBOX / ITILE, BATCH);
    fused_iou<<<g, TPB, 0, stream>>>(bboxes, angles, out);
}